// Round 1
// baseline (452.415 us; speedup 1.0000x reference)
//
#include <hip/hip_runtime.h>
#include <cstdint>
#include <cstddef>

#define NFEAT 128
#define TGRAPH 10
#define NGRAPHS 512
#define BN_EPS 1e-5f
#define BIN_CHUNK 2048
#define GSPAN 8    // max graphs a 128-row block can span
#define TSTR 24    // c_tile row stride in shorts: 48B rows, 16B-aligned, 2-way banks (free)

typedef __attribute__((ext_vector_type(8))) short bf16x8;
typedef __attribute__((ext_vector_type(4))) float f32x4;
typedef __attribute__((ext_vector_type(2))) float f32x2;

__device__ __forceinline__ float bf2f(short s) {
    union { unsigned u; float f; } c;
    c.u = ((unsigned)(unsigned short)s) << 16;
    return c.f;
}
__device__ __forceinline__ short f2bf(float f) {
    union { float f; unsigned u; } c;
    c.f = f;
    unsigned u = c.u;
    return (short)((u + 0x7fffu + ((u >> 16) & 1u)) >> 16);
}
// packed accumulate: both bf16 halves of dword v into a[0] (low) and a[1] (high)
// ext_vector add -> v_pk_add_f32 (1 inst for 2 adds): 3 VALU/dword vs 4 scalar
__device__ __forceinline__ void accp(f32x2& a, unsigned v) {
    union { unsigned u; float f; } lo, hi;
    lo.u = v << 16;
    hi.u = v & 0xffff0000u;
    f32x2 t;
    t[0] = lo.f;
    t[1] = hi.f;
    a += t;
}

// A-frag memory layout (shorts): buffer of 16-row tiles; element (row, k) lives at
//   ((row>>4)*4 + (k>>5))*512 + (((k>>3)&3)*16 + (row&15))*8 + (k&7)

// ---------------- CSR build, bucket-local (bucket = dst>>9, <=256 buckets) ----------------
__global__ void k_bucket_scan(const int* __restrict__ bhist, int* __restrict__ bbase,
                              int* __restrict__ cur256, int E) {
    __shared__ int s[256];
    int t = threadIdx.x;
    int v = bhist[t];
    s[t] = v;
    __syncthreads();
    for (int off = 1; off < 256; off <<= 1) {
        int x = 0;
        if (t >= off) x = s[t - off];
        __syncthreads();
        if (t >= off) s[t] += x;
        __syncthreads();
    }
    int excl = s[t] - v;
    bbase[t] = excl;
    cur256[t] = excl;
    if (t == 255) bbase[256] = E;
}

__global__ __launch_bounds__(256) void k_bin_scatter(const int* __restrict__ src,
                                                     const int* __restrict__ dst,
                                                     int* __restrict__ cur256,
                                                     int2* __restrict__ binned, int E) {
    __shared__ int hist[256];
    __shared__ int base[256];
    int t = threadIdx.x;
    int e0 = blockIdx.x * BIN_CHUNK;
    int e1 = min(e0 + BIN_CHUNK, E);
    hist[t] = 0;
    __syncthreads();
    for (int e = e0 + t; e < e1; e += 256) {
        int b = dst[e] >> 9;
        atomicAdd(&hist[b], 1);
    }
    __syncthreads();
    int c = hist[t];
    if (c > 0) base[t] = atomicAdd(&cur256[t], c);
    __syncthreads();
    hist[t] = 0;
    __syncthreads();
    for (int e = e0 + t; e < e1; e += 256) {
        int d = dst[e];
        int b = d >> 9;
        int loc = atomicAdd(&hist[b], 1);
        binned[base[b] + loc] = make_int2(src[e], d);
    }
}

__global__ __launch_bounds__(512) void k_bucket_csr(const int2* __restrict__ binned,
                                                    const int* __restrict__ bbase,
                                                    int* __restrict__ rowptr,
                                                    int* __restrict__ adj,
                                                    int N, int E, int nb) {
    __shared__ int deg[512];
    __shared__ int cur[512];
    int b = blockIdx.x;
    int t = threadIdx.x;
    int e0 = bbase[b], e1 = bbase[b + 1];
    deg[t] = 0;
    __syncthreads();
    for (int e = e0 + t; e < e1; e += 512)
        atomicAdd(&deg[binned[e].y & 511], 1);
    __syncthreads();
    int v = deg[t];
    for (int off = 1; off < 512; off <<= 1) {
        int x = 0;
        if (t >= off) x = deg[t - off];
        __syncthreads();
        if (t >= off) deg[t] += x;
        __syncthreads();
    }
    int excl = deg[t] - v;
    cur[t] = excl;
    int node = b * 512 + t;
    if (node < N) rowptr[node] = e0 + excl;
    if (b == nb - 1 && t == 0) rowptr[N] = E;
    __syncthreads();
    for (int e = e0 + t; e < e1; e += 512) {
        int2 p = binned[e];
        int loc = atomicAdd(&cur[p.y & 511], 1);
        adj[e0 + loc] = p.x;
    }
}

// ---------------- merged: bucket histogram + fp32->bf16 convert + weight frag prep -------
// blocks [0, hb): edge-bucket histogram; blocks [hb, ...): convert/prep (independent work,
// one dispatch instead of two)
__global__ __launch_bounds__(256) void k_prep_hist(const int* __restrict__ dst,
                                                   int* __restrict__ bhist, int E, int hb,
                                                   const float* __restrict__ x,
                                                   short* __restrict__ xbf,
                                                   const float* __restrict__ W0,
                                                   const float* __restrict__ W1,
                                                   const float* __restrict__ W2,
                                                   const float* __restrict__ W3,
                                                   short* __restrict__ Wf, int n4) {
    int t = threadIdx.x;
    if (blockIdx.x < hb) {
        __shared__ int h[256];
        h[t] = 0;
        __syncthreads();
        for (int e = blockIdx.x * 256 + t; e < E; e += hb * 256)
            atomicAdd(&h[dst[e] >> 9], 1);
        __syncthreads();
        if (h[t]) atomicAdd(&bhist[t], h[t]);
        return;
    }
    int i = (blockIdx.x - hb) * 256 + t;
    if (i < n4) {
        float4 v = ((const float4*)x)[i];
        ushort4 o;
        o.x = (unsigned short)f2bf(v.x);
        o.y = (unsigned short)f2bf(v.y);
        o.z = (unsigned short)f2bf(v.z);
        o.w = (unsigned short)f2bf(v.w);
        ((ushort4*)xbf)[i] = o;
    } else {
        int idx = i - n4;
        if (idx < 4 * 16384) {
            int w = idx >> 14, r = idx & 16383;
            int j = r & 7, lane = (r >> 3) & 63, ct = (r >> 9) & 7, kc = r >> 12;
            int k = kc * 32 + (lane >> 4) * 8 + j;
            int n = ct * 16 + (lane & 15);
            const float* W = (w == 0) ? W0 : (w == 1) ? W1 : (w == 2) ? W2 : W3;
            Wf[idx] = f2bf(W[k * NFEAT + n]);
        }
    }
}

// ---------------- fused: neighborhood aggregation -> A-frags -> MFMA GEMM + stats --------
// MFMA 16x16x32 A-frag: lane(quad,l16) holds row l16, k = kc*32 + quad*8 + j, i.e. the
// contiguous byte slice [kc*64 + quad*16, +16) of the row == uint4 index kc*4+quad.
// So lane(quad,l16) accumulates its own 64B slice (4 uint4, p==quad mod 4) of every
// neighbor row of node (row_base + rt*16 + l16) straight into fragment registers.
// The 4 lanes of a quad-column issue one 64B-coalesced request per uint4 column.
// This replaces k_aggregate_v4 + the STATS/FRAG_OUT GEMM: saves ag write (25.6MB) +
// ag read (25.6MB) per layer and one dispatch; gather VALU overlaps MFMA across waves.
__global__ __launch_bounds__(256) void k_agg_gemm(const short* __restrict__ X,
                                                  const int* __restrict__ rowptr,
                                                  const int* __restrict__ adj,
                                                  const short* __restrict__ Wf,
                                                  const float* __restrict__ bias,
                                                  float* __restrict__ stats,
                                                  short* __restrict__ C, int N) {
    __shared__ float s_aux[256];           // stats: sum | sq
    __shared__ short c_tile[4][32 * TSTR]; // per-wave 32-row C staging, padded stride
    int tid = threadIdx.x;
    int wave = tid >> 6, lane = tid & 63;
    int quad = lane >> 4, l16 = lane & 15;
    int row_base = blockIdx.x * 128 + wave * 32;

    s_aux[tid] = 0.f;
    __syncthreads();

    const uint4* Xv = (const uint4*)X;  // one row = 16 uint4

    bf16x8 afrag[2][4];
#pragma unroll
    for (int rt = 0; rt < 2; ++rt) {
        f32x2 acc[4][4];  // [kc][dword pair] = 8 floats per kc chunk
#pragma unroll
        for (int kc = 0; kc < 4; ++kc)
#pragma unroll
            for (int m = 0; m < 4; ++m) acc[kc][m] = (f32x2){0.f, 0.f};
        int r = row_base + rt * 16 + l16;
        if (r < N) {
            // self row (GIN eps=0: x + sum(neighbors))
            size_t rb = (size_t)r * 16 + quad;
#pragma unroll
            for (int kc = 0; kc < 4; ++kc) {
                uint4 v = Xv[rb + kc * 4];
                accp(acc[kc][0], v.x); accp(acc[kc][1], v.y);
                accp(acc[kc][2], v.z); accp(acc[kc][3], v.w);
            }
            int e = rowptr[r], e1 = rowptr[r + 1];
            // 2-deep unroll: 8 uint4 gathers in flight per lane
            for (; e + 2 <= e1; e += 2) {
                size_t n0 = (size_t)adj[e] * 16 + quad;
                size_t n1 = (size_t)adj[e + 1] * 16 + quad;
                uint4 u0[4], u1[4];
#pragma unroll
                for (int kc = 0; kc < 4; ++kc) u0[kc] = Xv[n0 + kc * 4];
#pragma unroll
                for (int kc = 0; kc < 4; ++kc) u1[kc] = Xv[n1 + kc * 4];
#pragma unroll
                for (int kc = 0; kc < 4; ++kc) {
                    accp(acc[kc][0], u0[kc].x); accp(acc[kc][1], u0[kc].y);
                    accp(acc[kc][2], u0[kc].z); accp(acc[kc][3], u0[kc].w);
                    accp(acc[kc][0], u1[kc].x); accp(acc[kc][1], u1[kc].y);
                    accp(acc[kc][2], u1[kc].z); accp(acc[kc][3], u1[kc].w);
                }
            }
            if (e < e1) {
                size_t n0 = (size_t)adj[e] * 16 + quad;
#pragma unroll
                for (int kc = 0; kc < 4; ++kc) {
                    uint4 v = Xv[n0 + kc * 4];
                    accp(acc[kc][0], v.x); accp(acc[kc][1], v.y);
                    accp(acc[kc][2], v.z); accp(acc[kc][3], v.w);
                }
            }
        }
        // pack to bf16 A-frags (single rounding, same as old aggregate->frag path)
#pragma unroll
        for (int kc = 0; kc < 4; ++kc) {
            bf16x8 f;
#pragma unroll
            for (int m = 0; m < 4; ++m) {
                f[2 * m] = f2bf(acc[kc][m][0]);
                f[2 * m + 1] = f2bf(acc[kc][m][1]);
            }
            afrag[rt][kc] = f;
        }
    }

    f32x4 acc[2][8];
#pragma unroll
    for (int i = 0; i < 2; i++)
#pragma unroll
        for (int j = 0; j < 8; j++) acc[i][j] = (f32x4){0.f, 0.f, 0.f, 0.f};

#pragma unroll
    for (int kc = 0; kc < 4; ++kc) {
        const short* wp = Wf + ((size_t)(kc * 8) * 64 + lane) * 8;
#pragma unroll
        for (int ct = 0; ct < 8; ++ct) {
            bf16x8 b = *(const bf16x8*)(wp + (size_t)ct * 64 * 8);
            acc[0][ct] = __builtin_amdgcn_mfma_f32_16x16x32_bf16(afrag[0][kc], b, acc[0][ct], 0, 0, 0);
            acc[1][ct] = __builtin_amdgcn_mfma_f32_16x16x32_bf16(afrag[1][kc], b, acc[1][ct], 0, 0, 0);
        }
    }

    // epilogue: bias + BN stats + frag-layout store (C/D: col = ct*16+l16,
    // local row = rt*16 + quad*4 + reg)
    short* tile = &c_tile[wave][0];
    int row2 = lane >> 1, half = lane & 1;
#pragma unroll
    for (int ct = 0; ct < 8; ++ct) {
        int col = ct * 16 + l16;
        float bv = bias[col];
        float ls = 0.f, ls2 = 0.f;
#pragma unroll
        for (int rt = 0; rt < 2; ++rt) {
#pragma unroll
            for (int reg = 0; reg < 4; ++reg) {
                int lrow = rt * 16 + quad * 4 + reg;
                float v = acc[rt][ct][reg] + bv;
                if (row_base + lrow < N) { ls += v; ls2 += v * v; }
                tile[lrow * TSTR + l16] = f2bf(v);
            }
        }
        ls += __shfl_xor(ls, 16);
        ls += __shfl_xor(ls, 32);
        ls2 += __shfl_xor(ls2, 16);
        ls2 += __shfl_xor(ls2, 32);
        if (quad == 0) {
            atomicAdd(&s_aux[col], ls);
            atomicAdd(&s_aux[NFEAT + col], ls2);
        }
        // wave-private tile: same-wave DS ordering suffices, no barrier
        uint4 val = *(const uint4*)(tile + row2 * TSTR + half * 8);
        int grow = row_base + row2;
        if (grow < N) {
            int col0 = ct * 16 + half * 8;
            size_t addr = ((size_t)(grow >> 4) * 4 + (col0 >> 5)) * 512 +
                          (size_t)((((col0 >> 3) & 3) * 16 + (grow & 15)) * 8);
            *(uint4*)(C + addr) = val;
        }
    }

    __syncthreads();
    if (tid < NFEAT) {
        atomicAdd(&stats[tid], s_aux[tid]);
        atomicAdd(&stats[NFEAT + tid], s_aux[NFEAT + tid]);
    }
}

// ---------------- MFMA GEMM (B-side): BN+ReLU on input frags; opt. fused pool -----------
template <bool BN_RELU_IN, bool RELU_OUT, bool STATS, bool FRAG_OUT, bool POOL>
__global__ __launch_bounds__(256) void k_gemm_mfma(const short* __restrict__ A,
                                                   const short* __restrict__ Wf,
                                                   const float* __restrict__ bias,
                                                   float* __restrict__ stats,
                                                   const float* __restrict__ gamma,
                                                   const float* __restrict__ beta,
                                                   const int* __restrict__ batch,
                                                   float* __restrict__ pooled,
                                                   short* __restrict__ C, int N) {
    __shared__ float s_aux[256];           // STATS: sum|sq ; BN: scale|shift
    __shared__ short c_tile[4][32 * TSTR]; // per-wave 32-row C staging, padded stride
    __shared__ float s_pool[GSPAN][NFEAT];
    int tid = threadIdx.x;
    int wave = tid >> 6, lane = tid & 63;
    int quad = lane >> 4, l16 = lane & 15;
    int row_base = blockIdx.x * 128 + wave * 32;

    int gbase = 0;
    if constexpr (POOL) {
        int first = blockIdx.x * 128;
        gbase = (first < N) ? batch[first] : 0;
        for (int i = tid; i < GSPAN * NFEAT; i += 256) s_pool[i >> 7][i & 127] = 0.f;
    }
    if constexpr (STATS) s_aux[tid] = 0.f;
    if constexpr (BN_RELU_IN) {
        if (tid < NFEAT) {
            float mean = stats[tid] / (float)N;
            float var = stats[NFEAT + tid] / (float)N - mean * mean;
            float inv = rsqrtf(var + BN_EPS);
            float sc = gamma[tid] * inv;
            s_aux[tid] = sc;
            s_aux[NFEAT + tid] = beta[tid] - mean * sc;
        }
    }
    if constexpr (STATS || BN_RELU_IN || POOL) __syncthreads();

    f32x4 acc[2][8];
#pragma unroll
    for (int i = 0; i < 2; i++)
#pragma unroll
        for (int j = 0; j < 8; j++) acc[i][j] = (f32x4){0.f, 0.f, 0.f, 0.f};

    const short* af = A + ((size_t)(blockIdx.x * 8 + wave * 2) * 4) * 512;

#pragma unroll
    for (int kc = 0; kc < 4; ++kc) {
        bf16x8 a0 = *(const bf16x8*)(af + (size_t)kc * 512 + lane * 8);
        bf16x8 a1 = *(const bf16x8*)(af + (size_t)(4 + kc) * 512 + lane * 8);
        if constexpr (BN_RELU_IN) {
            int koff = kc * 32 + quad * 8;
#pragma unroll
            for (int j = 0; j < 8; j++) {
                float sc = s_aux[koff + j];
                float sh = s_aux[NFEAT + koff + j];
                a0[j] = f2bf(fmaxf(bf2f(a0[j]) * sc + sh, 0.f));
                a1[j] = f2bf(fmaxf(bf2f(a1[j]) * sc + sh, 0.f));
            }
        }
        const short* wp = Wf + ((size_t)(kc * 8) * 64 + lane) * 8;
#pragma unroll
        for (int ct = 0; ct < 8; ++ct) {
            bf16x8 b = *(const bf16x8*)(wp + (size_t)ct * 64 * 8);
            acc[0][ct] = __builtin_amdgcn_mfma_f32_16x16x32_bf16(a0, b, acc[0][ct], 0, 0, 0);
            acc[1][ct] = __builtin_amdgcn_mfma_f32_16x16x32_bf16(a1, b, acc[1][ct], 0, 0, 0);
        }
    }

    // graph index per (rt,reg) row, hoisted (POOL only)
    int dg[8];
    if constexpr (POOL) {
#pragma unroll
        for (int rt = 0; rt < 2; ++rt)
#pragma unroll
            for (int reg = 0; reg < 4; ++reg) {
                int row = row_base + rt * 16 + quad * 4 + reg;
                dg[rt * 4 + reg] = (row < N) ? (batch[row] - gbase) : -1;
            }
    }

    // C/D layout: col = ct*16 + l16, local row = rt*16 + quad*4 + reg
    short* tile = &c_tile[wave][0];
    int row2 = lane >> 1, half = lane & 1;
#pragma unroll
    for (int ct = 0; ct < 8; ++ct) {
        int col = ct * 16 + l16;
        float bv = bias[col];
        float ls = 0.f, ls2 = 0.f;
        int cg = -1;
        float ps = 0.f;
#pragma unroll
        for (int rt = 0; rt < 2; ++rt) {
#pragma unroll
            for (int reg = 0; reg < 4; ++reg) {
                int lrow = rt * 16 + quad * 4 + reg;
                float v = acc[rt][ct][reg] + bv;
                if constexpr (RELU_OUT) v = fmaxf(v, 0.f);
                if constexpr (STATS) {
                    if (row_base + lrow < N) { ls += v; ls2 += v * v; }
                }
                if constexpr (POOL) {
                    int d = dg[rt * 4 + reg];
                    if (d != cg) {
                        if (cg >= 0) atomicAdd(&s_pool[cg & (GSPAN - 1)][col], ps);
                        cg = d; ps = 0.f;
                    }
                    if (d >= 0) ps += v;
                } else {
                    tile[lrow * TSTR + l16] = f2bf(v);
                }
            }
        }
        if constexpr (POOL) {
            if (cg >= 0) atomicAdd(&s_pool[cg & (GSPAN - 1)][col], ps);
        }
        if constexpr (STATS) {
            ls += __shfl_xor(ls, 16);
            ls += __shfl_xor(ls, 32);
            ls2 += __shfl_xor(ls2, 16);
            ls2 += __shfl_xor(ls2, 32);
            if (quad == 0) {
                atomicAdd(&s_aux[col], ls);
                atomicAdd(&s_aux[NFEAT + col], ls2);
            }
        }
        if constexpr (!POOL) {
            // wave-private tile: same-wave DS ordering suffices, no barrier
            uint4 val = *(const uint4*)(tile + row2 * TSTR + half * 8);
            int grow = row_base + row2;
            if (grow < N) {
                int col0 = ct * 16 + half * 8;
                if constexpr (FRAG_OUT) {
                    size_t addr = ((size_t)(grow >> 4) * 4 + (col0 >> 5)) * 512 +
                                  (size_t)((((col0 >> 3) & 3) * 16 + (grow & 15)) * 8);
                    *(uint4*)(C + addr) = val;
                } else {
                    *(uint4*)(C + (size_t)grow * NFEAT + col0) = val;
                }
            }
        }
    }

    if constexpr (STATS) {
        __syncthreads();
        if (tid < NFEAT) {
            atomicAdd(&stats[tid], s_aux[tid]);
            atomicAdd(&stats[NFEAT + tid], s_aux[NFEAT + tid]);
        }
    }
    if constexpr (POOL) {
        __syncthreads();
        for (int i = tid; i < GSPAN * NFEAT; i += 256) {
            float v = s_pool[i >> 7][i & 127];
            if (v != 0.f) {
                int gg = gbase + (i >> 7);
                if (gg < NGRAPHS) atomicAdd(&pooled[gg * NFEAT + (i & 127)], v);
            }
        }
    }
}

__global__ void k_final(const float* __restrict__ pooled, const float* __restrict__ Wl,
                        const float* __restrict__ bl, float* __restrict__ out) {
    int idx = blockIdx.x * blockDim.x + threadIdx.x;
    if (idx >= NGRAPHS * TGRAPH) return;
    int g = idx / TGRAPH, t = idx % TGRAPH;
    const float* p = pooled + (size_t)g * NFEAT;
    float acc = bl[t];
#pragma unroll 16
    for (int k = 0; k < NFEAT; ++k) acc += p[k] * Wl[k * TGRAPH + t];
    out[idx] = acc;
}

extern "C" void kernel_launch(void* const* d_in, const int* in_sizes, int n_in,
                              void* d_out, int out_size, void* d_ws, size_t ws_size,
                              hipStream_t stream) {
    const float* x = (const float*)d_in[0];
    const int* ei = (const int*)d_in[1];
    const int* batch = (const int*)d_in[2];
    const float* W1a = (const float*)d_in[3];
    const float* b1a = (const float*)d_in[4];
    const float* g1 = (const float*)d_in[5];
    const float* bt1 = (const float*)d_in[6];
    const float* W1b = (const float*)d_in[7];
    const float* b1b = (const float*)d_in[8];
    const float* W2a = (const float*)d_in[9];
    const float* b2a = (const float*)d_in[10];
    const float* g2 = (const float*)d_in[11];
    const float* bt2 = (const float*)d_in[12];
    const float* W2b = (const float*)d_in[13];
    const float* b2b = (const float*)d_in[14];
    const float* Wl = (const float*)d_in[15];
    const float* bl = (const float*)d_in[16];
    float* out = (float*)d_out;

    int N = in_sizes[2];
    int E = in_sizes[1] / 2;
    int nb = (N + 511) >> 9;
    const int* src = ei;
    const int* dst = ei + E;

    int gemmBlocks = (N + 127) / 128;
    int padRows = gemmBlocks * 128;

    char* ws = (char*)d_ws;
    size_t off = 0;
    auto alloc = [&](size_t bytes) -> void* {
        void* p = ws + off;
        off = (off + bytes + 255) & ~(size_t)255;
        return p;
    };
    short* xbf = (short*)alloc((size_t)N * NFEAT * 2);        // row-major (gather input)
    short* ybf = (short*)alloc((size_t)padRows * NFEAT * 2);  // frag layout
    short* hbf = (short*)alloc((size_t)N * NFEAT * 2);        // row-major (gather input)
    short* Wf = (short*)alloc((size_t)4 * 16384 * 2);
    int* adj = (int*)alloc((size_t)E * 4);
    int2* binned = (int2*)alloc((size_t)E * 8);
    int* rowptr = (int*)alloc((size_t)(N + 1) * 4);
    int* bbase = (int*)alloc(257 * 4);
    int* cur256 = (int*)alloc(256 * 4);
    // zero-region: bhist + stats1 + stats2 + pooled
    int* bhist = (int*)alloc(256 * 4);
    float* stats1 = (float*)alloc(256 * 4);
    float* stats2 = (float*)alloc(256 * 4);
    float* pooled = (float*)alloc((size_t)NGRAPHS * NFEAT * 4);
    size_t zbytes = (char*)(pooled + (size_t)NGRAPHS * NFEAT) - (char*)bhist;

    hipMemsetAsync(bhist, 0, zbytes, stream);

    // ---- merged hist + dtype prep (one dispatch), then CSR chain ----
    int n4 = N * NFEAT / 4;
    int prepTot = n4 + 4 * 16384;
    int hb = 784;
    k_prep_hist<<<hb + (prepTot + 255) / 256, 256, 0, stream>>>(
        dst, bhist, E, hb, x, xbf, W1a, W1b, W2a, W2b, Wf, n4);
    k_bucket_scan<<<1, 256, 0, stream>>>(bhist, bbase, cur256, E);
    k_bin_scatter<<<(E + BIN_CHUNK - 1) / BIN_CHUNK, 256, 0, stream>>>(src, dst, cur256, binned, E);
    k_bucket_csr<<<nb, 512, 0, stream>>>(binned, bbase, rowptr, adj, N, E, nb);

    // ---- layer 1: fused aggregate+GEMM-a, then BN+ReLU GEMM-b ----
    k_agg_gemm<<<gemmBlocks, 256, 0, stream>>>(xbf, rowptr, adj, Wf + 0 * 16384, b1a,
                                               stats1, ybf, N);
    k_gemm_mfma<true, true, false, false, false><<<gemmBlocks, 256, 0, stream>>>(
        ybf, Wf + 1 * 16384, b1b, stats1, g1, bt1, nullptr, nullptr, hbf, N);

    // ---- layer 2 (GEMM-b pools directly) ----
    k_agg_gemm<<<gemmBlocks, 256, 0, stream>>>(hbf, rowptr, adj, Wf + 2 * 16384, b2a,
                                               stats2, ybf, N);
    k_gemm_mfma<true, true, false, false, true><<<gemmBlocks, 256, 0, stream>>>(
        ybf, Wf + 3 * 16384, b2b, stats2, g2, bt2, batch, pooled, nullptr, N);

    // ---- classifier ----
    k_final<<<(NGRAPHS * TGRAPH + 255) / 256, 256, 0, stream>>>(pooled, Wl, bl, out);
}

// Round 2
// 445.291 us; speedup vs baseline: 1.0160x; 1.0160x over previous
//
#include <hip/hip_runtime.h>
#include <cstdint>
#include <cstddef>

#define NFEAT 128
#define TGRAPH 10
#define NGRAPHS 512
#define BN_EPS 1e-5f
#define BIN_CHUNK 2048
#define GSPAN 8    // max graphs a 128-row block can span
#define TSTR 24    // c_tile row stride in shorts (k_gemm_mfma): 48B rows, 2-way banks (free)
#define ATSTR 40   // k_agg_gemm c_tile row stride in shorts: 32 cols + 8 pad

typedef __attribute__((ext_vector_type(8))) short bf16x8;
typedef __attribute__((ext_vector_type(4))) float f32x4;
typedef __attribute__((ext_vector_type(2))) float f32x2;

__device__ __forceinline__ float bf2f(short s) {
    union { unsigned u; float f; } c;
    c.u = ((unsigned)(unsigned short)s) << 16;
    return c.f;
}
__device__ __forceinline__ short f2bf(float f) {
    union { float f; unsigned u; } c;
    c.f = f;
    unsigned u = c.u;
    return (short)((u + 0x7fffu + ((u >> 16) & 1u)) >> 16);
}
// packed accumulate: both bf16 halves of dword v into a[0] (low) and a[1] (high)
__device__ __forceinline__ void accp(f32x2& a, unsigned v) {
    union { unsigned u; float f; } lo, hi;
    lo.u = v << 16;
    hi.u = v & 0xffff0000u;
    f32x2 t;
    t[0] = lo.f;
    t[1] = hi.f;
    a += t;
}

// A-frag memory layout (shorts): buffer of 16-row tiles; element (row, k) lives at
//   ((row>>4)*4 + (k>>5))*512 + (((k>>3)&3)*16 + (row&15))*8 + (k&7)

// ---------------- CSR build, bucket-local (bucket = dst>>9, <=256 buckets) ----------------
__global__ void k_bucket_scan(const int* __restrict__ bhist, int* __restrict__ bbase,
                              int* __restrict__ cur256, int E) {
    __shared__ int s[256];
    int t = threadIdx.x;
    int v = bhist[t];
    s[t] = v;
    __syncthreads();
    for (int off = 1; off < 256; off <<= 1) {
        int x = 0;
        if (t >= off) x = s[t - off];
        __syncthreads();
        if (t >= off) s[t] += x;
        __syncthreads();
    }
    int excl = s[t] - v;
    bbase[t] = excl;
    cur256[t] = excl;
    if (t == 255) bbase[256] = E;
}

__global__ __launch_bounds__(256) void k_bin_scatter(const int* __restrict__ src,
                                                     const int* __restrict__ dst,
                                                     int* __restrict__ cur256,
                                                     int2* __restrict__ binned, int E) {
    __shared__ int hist[256];
    __shared__ int base[256];
    int t = threadIdx.x;
    int e0 = blockIdx.x * BIN_CHUNK;
    int e1 = min(e0 + BIN_CHUNK, E);
    hist[t] = 0;
    __syncthreads();
    for (int e = e0 + t; e < e1; e += 256) {
        int b = dst[e] >> 9;
        atomicAdd(&hist[b], 1);
    }
    __syncthreads();
    int c = hist[t];
    if (c > 0) base[t] = atomicAdd(&cur256[t], c);
    __syncthreads();
    hist[t] = 0;
    __syncthreads();
    for (int e = e0 + t; e < e1; e += 256) {
        int d = dst[e];
        int b = d >> 9;
        int loc = atomicAdd(&hist[b], 1);
        binned[base[b] + loc] = make_int2(src[e], d);
    }
}

__global__ __launch_bounds__(512) void k_bucket_csr(const int2* __restrict__ binned,
                                                    const int* __restrict__ bbase,
                                                    int* __restrict__ rowptr,
                                                    int* __restrict__ adj,
                                                    int N, int E, int nb) {
    __shared__ int deg[512];
    __shared__ int cur[512];
    int b = blockIdx.x;
    int t = threadIdx.x;
    int e0 = bbase[b], e1 = bbase[b + 1];
    deg[t] = 0;
    __syncthreads();
    for (int e = e0 + t; e < e1; e += 512)
        atomicAdd(&deg[binned[e].y & 511], 1);
    __syncthreads();
    int v = deg[t];
    for (int off = 1; off < 512; off <<= 1) {
        int x = 0;
        if (t >= off) x = deg[t - off];
        __syncthreads();
        if (t >= off) deg[t] += x;
        __syncthreads();
    }
    int excl = deg[t] - v;
    cur[t] = excl;
    int node = b * 512 + t;
    if (node < N) rowptr[node] = e0 + excl;
    if (b == nb - 1 && t == 0) rowptr[N] = E;
    __syncthreads();
    for (int e = e0 + t; e < e1; e += 512) {
        int2 p = binned[e];
        int loc = atomicAdd(&cur[p.y & 511], 1);
        adj[e0 + loc] = p.x;
    }
}

// ---------------- merged: bucket histogram + fp32->bf16 convert + weight frag prep -------
__global__ __launch_bounds__(256) void k_prep_hist(const int* __restrict__ dst,
                                                   int* __restrict__ bhist, int E, int hb,
                                                   const float* __restrict__ x,
                                                   short* __restrict__ xbf,
                                                   const float* __restrict__ W0,
                                                   const float* __restrict__ W1,
                                                   const float* __restrict__ W2,
                                                   const float* __restrict__ W3,
                                                   short* __restrict__ Wf, int n4) {
    int t = threadIdx.x;
    if (blockIdx.x < hb) {
        __shared__ int h[256];
        h[t] = 0;
        __syncthreads();
        for (int e = blockIdx.x * 256 + t; e < E; e += hb * 256)
            atomicAdd(&h[dst[e] >> 9], 1);
        __syncthreads();
        if (h[t]) atomicAdd(&bhist[t], h[t]);
        return;
    }
    int i = (blockIdx.x - hb) * 256 + t;
    if (i < n4) {
        float4 v = ((const float4*)x)[i];
        ushort4 o;
        o.x = (unsigned short)f2bf(v.x);
        o.y = (unsigned short)f2bf(v.y);
        o.z = (unsigned short)f2bf(v.z);
        o.w = (unsigned short)f2bf(v.w);
        ((ushort4*)xbf)[i] = o;
    } else {
        int idx = i - n4;
        if (idx < 4 * 16384) {
            int w = idx >> 14, r = idx & 16383;
            int j = r & 7, lane = (r >> 3) & 63, ct = (r >> 9) & 7, kc = r >> 12;
            int k = kc * 32 + (lane >> 4) * 8 + j;
            int n = ct * 16 + (lane & 15);
            const float* W = (w == 0) ? W0 : (w == 1) ? W1 : (w == 2) ? W2 : W3;
            Wf[idx] = f2bf(W[k * NFEAT + n]);
        }
    }
}

// ---------------- fused: neighborhood aggregation -> A-frags -> MFMA GEMM + stats --------
// R1 restructure vs R0 (110us, Occ 15%, 1.97 TB/s -- latency/tail-bound):
//  * 64-row blocks, ONE row per l16 lane (16 rows/wave): 1563 blocks x 4 waves = 6252
//    waves (2x R0), shorter waves -> smaller degree-imbalance tail.
//  * adj software pipeline: next iteration's 2 adj indices prefetched while current
//    X gathers are in flight -- removes L2(adj)+HBM(X) serial chain per iteration.
//  * lane(quad,l16): row r = row_base+l16, slice quad. For fixed kc the 4 quads read
//    4 consecutive uint4 = 64B contiguous per neighbor row (coalesced).
__global__ __launch_bounds__(256) void k_agg_gemm(const short* __restrict__ X,
                                                  const int* __restrict__ rowptr,
                                                  const int* __restrict__ adj,
                                                  const short* __restrict__ Wf,
                                                  const float* __restrict__ bias,
                                                  float* __restrict__ stats,
                                                  short* __restrict__ C, int N) {
    __shared__ float s_aux[256];            // stats: sum | sq
    __shared__ short c_tile[4][16 * ATSTR]; // per-wave 16-row x 32-col C staging
    int tid = threadIdx.x;
    int wave = tid >> 6, lane = tid & 63;
    int quad = lane >> 4, l16 = lane & 15;
    int row_base = blockIdx.x * 64 + wave * 16;

    s_aux[tid] = 0.f;
    __syncthreads();

    const uint4* Xv = (const uint4*)X;  // one row = 16 uint4

    f32x2 acc[4][4];  // [kc][dword] : 8 f32 per kc chunk = this lane's 16B row slice
#pragma unroll
    for (int kc = 0; kc < 4; ++kc)
#pragma unroll
        for (int m = 0; m < 4; ++m) acc[kc][m] = (f32x2){0.f, 0.f};

    int r = row_base + l16;
    if (r < N) {
        // self row (GIN eps=0: x + sum(neighbors))
        size_t rb = (size_t)r * 16 + quad;
#pragma unroll
        for (int kc = 0; kc < 4; ++kc) {
            uint4 v = Xv[rb + kc * 4];
            accp(acc[kc][0], v.x); accp(acc[kc][1], v.y);
            accp(acc[kc][2], v.z); accp(acc[kc][3], v.w);
        }
        int e0 = rowptr[r], e1 = rowptr[r + 1];
        // adj 1-iteration-ahead pipeline; 8 X-gathers in flight per lane
        int a0 = (e0 < e1) ? adj[e0] : 0;
        int a1 = (e0 + 1 < e1) ? adj[e0 + 1] : -1;
        for (int e = e0; e < e1; e += 2) {
            int p0 = a0;
            int p1 = a1;
            a0 = (e + 2 < e1) ? adj[e + 2] : 0;
            a1 = (e + 3 < e1) ? adj[e + 3] : -1;
            size_t n0 = (size_t)p0 * 16 + quad;
            uint4 u0[4], u1[4];
#pragma unroll
            for (int kc = 0; kc < 4; ++kc) u0[kc] = Xv[n0 + kc * 4];
            if (p1 >= 0) {
                size_t n1 = (size_t)p1 * 16 + quad;
#pragma unroll
                for (int kc = 0; kc < 4; ++kc) u1[kc] = Xv[n1 + kc * 4];
            } else {
#pragma unroll
                for (int kc = 0; kc < 4; ++kc) u1[kc] = make_uint4(0u, 0u, 0u, 0u);
            }
#pragma unroll
            for (int kc = 0; kc < 4; ++kc) {
                accp(acc[kc][0], u0[kc].x); accp(acc[kc][1], u0[kc].y);
                accp(acc[kc][2], u0[kc].z); accp(acc[kc][3], u0[kc].w);
                accp(acc[kc][0], u1[kc].x); accp(acc[kc][1], u1[kc].y);
                accp(acc[kc][2], u1[kc].z); accp(acc[kc][3], u1[kc].w);
            }
        }
    }

    // pack to bf16 A-frags (single rounding, as before)
    bf16x8 afrag[4];
#pragma unroll
    for (int kc = 0; kc < 4; ++kc) {
        bf16x8 f;
#pragma unroll
        for (int m = 0; m < 4; ++m) {
            f[2 * m] = f2bf(acc[kc][m][0]);
            f[2 * m + 1] = f2bf(acc[kc][m][1]);
        }
        afrag[kc] = f;
    }

    f32x4 oacc[8];
#pragma unroll
    for (int j = 0; j < 8; j++) oacc[j] = (f32x4){0.f, 0.f, 0.f, 0.f};

#pragma unroll
    for (int kc = 0; kc < 4; ++kc) {
        const short* wp = Wf + ((size_t)(kc * 8) * 64 + lane) * 8;
#pragma unroll
        for (int ct = 0; ct < 8; ++ct) {
            bf16x8 b = *(const bf16x8*)(wp + (size_t)ct * 64 * 8);
            oacc[ct] = __builtin_amdgcn_mfma_f32_16x16x32_bf16(afrag[kc], b, oacc[ct], 0, 0, 0);
        }
    }

    // epilogue: bias + BN stats + frag-layout store.
    // C/D layout: col = ct*16 + l16, local row = quad*4 + reg (16 rows/wave).
    // ct processed in pairs: stage 16x32 in LDS, then all 64 lanes read one uint4.
    short* tile = &c_tile[wave][0];
    int row2 = lane >> 2, q2 = lane & 3;
#pragma unroll
    for (int ct = 0; ct < 8; ++ct) {
        int col = ct * 16 + l16;
        float bv = bias[col];
        float ls = 0.f, ls2 = 0.f;
#pragma unroll
        for (int reg = 0; reg < 4; ++reg) {
            int lrow = quad * 4 + reg;
            float v = oacc[ct][reg] + bv;
            if (row_base + lrow < N) { ls += v; ls2 += v * v; }
            tile[lrow * ATSTR + (ct & 1) * 16 + l16] = f2bf(v);
        }
        ls += __shfl_xor(ls, 16);
        ls += __shfl_xor(ls, 32);
        ls2 += __shfl_xor(ls2, 16);
        ls2 += __shfl_xor(ls2, 32);
        if (quad == 0) {
            atomicAdd(&s_aux[col], ls);
            atomicAdd(&s_aux[NFEAT + col], ls2);
        }
        if (ct & 1) {
            // wave-private tile: same-wave DS ordering suffices, no barrier
            uint4 val = *(const uint4*)(tile + row2 * ATSTR + q2 * 8);
            int grow = row_base + row2;
            if (grow < N) {
                int col0 = (ct - 1) * 16 + q2 * 8;
                size_t addr = ((size_t)(grow >> 4) * 4 + (col0 >> 5)) * 512 +
                              (size_t)((((col0 >> 3) & 3) * 16 + (grow & 15)) * 8);
                *(uint4*)(C + addr) = val;
            }
        }
    }

    __syncthreads();
    if (tid < NFEAT) {
        atomicAdd(&stats[tid], s_aux[tid]);
        atomicAdd(&stats[NFEAT + tid], s_aux[NFEAT + tid]);
    }
}

// ---------------- MFMA GEMM (B-side): BN+ReLU on input frags; opt. fused pool -----------
template <bool BN_RELU_IN, bool RELU_OUT, bool STATS, bool FRAG_OUT, bool POOL>
__global__ __launch_bounds__(256) void k_gemm_mfma(const short* __restrict__ A,
                                                   const short* __restrict__ Wf,
                                                   const float* __restrict__ bias,
                                                   float* __restrict__ stats,
                                                   const float* __restrict__ gamma,
                                                   const float* __restrict__ beta,
                                                   const int* __restrict__ batch,
                                                   float* __restrict__ pooled,
                                                   short* __restrict__ C, int N) {
    __shared__ float s_aux[256];           // STATS: sum|sq ; BN: scale|shift
    __shared__ short c_tile[4][32 * TSTR]; // per-wave 32-row C staging, padded stride
    __shared__ float s_pool[GSPAN][NFEAT];
    int tid = threadIdx.x;
    int wave = tid >> 6, lane = tid & 63;
    int quad = lane >> 4, l16 = lane & 15;
    int row_base = blockIdx.x * 128 + wave * 32;

    int gbase = 0;
    if constexpr (POOL) {
        int first = blockIdx.x * 128;
        gbase = (first < N) ? batch[first] : 0;
        for (int i = tid; i < GSPAN * NFEAT; i += 256) s_pool[i >> 7][i & 127] = 0.f;
    }
    if constexpr (STATS) s_aux[tid] = 0.f;
    if constexpr (BN_RELU_IN) {
        if (tid < NFEAT) {
            float mean = stats[tid] / (float)N;
            float var = stats[NFEAT + tid] / (float)N - mean * mean;
            float inv = rsqrtf(var + BN_EPS);
            float sc = gamma[tid] * inv;
            s_aux[tid] = sc;
            s_aux[NFEAT + tid] = beta[tid] - mean * sc;
        }
    }
    if constexpr (STATS || BN_RELU_IN || POOL) __syncthreads();

    f32x4 acc[2][8];
#pragma unroll
    for (int i = 0; i < 2; i++)
#pragma unroll
        for (int j = 0; j < 8; j++) acc[i][j] = (f32x4){0.f, 0.f, 0.f, 0.f};

    const short* af = A + ((size_t)(blockIdx.x * 8 + wave * 2) * 4) * 512;

#pragma unroll
    for (int kc = 0; kc < 4; ++kc) {
        bf16x8 a0 = *(const bf16x8*)(af + (size_t)kc * 512 + lane * 8);
        bf16x8 a1 = *(const bf16x8*)(af + (size_t)(4 + kc) * 512 + lane * 8);
        if constexpr (BN_RELU_IN) {
            int koff = kc * 32 + quad * 8;
#pragma unroll
            for (int j = 0; j < 8; j++) {
                float sc = s_aux[koff + j];
                float sh = s_aux[NFEAT + koff + j];
                a0[j] = f2bf(fmaxf(bf2f(a0[j]) * sc + sh, 0.f));
                a1[j] = f2bf(fmaxf(bf2f(a1[j]) * sc + sh, 0.f));
            }
        }
        const short* wp = Wf + ((size_t)(kc * 8) * 64 + lane) * 8;
#pragma unroll
        for (int ct = 0; ct < 8; ++ct) {
            bf16x8 b = *(const bf16x8*)(wp + (size_t)ct * 64 * 8);
            acc[0][ct] = __builtin_amdgcn_mfma_f32_16x16x32_bf16(a0, b, acc[0][ct], 0, 0, 0);
            acc[1][ct] = __builtin_amdgcn_mfma_f32_16x16x32_bf16(a1, b, acc[1][ct], 0, 0, 0);
        }
    }

    // graph index per (rt,reg) row, hoisted (POOL only)
    int dg[8];
    if constexpr (POOL) {
#pragma unroll
        for (int rt = 0; rt < 2; ++rt)
#pragma unroll
            for (int reg = 0; reg < 4; ++reg) {
                int row = row_base + rt * 16 + quad * 4 + reg;
                dg[rt * 4 + reg] = (row < N) ? (batch[row] - gbase) : -1;
            }
    }

    // C/D layout: col = ct*16 + l16, local row = rt*16 + quad*4 + reg
    short* tile = &c_tile[wave][0];
    int row2 = lane >> 1, half = lane & 1;
#pragma unroll
    for (int ct = 0; ct < 8; ++ct) {
        int col = ct * 16 + l16;
        float bv = bias[col];
        float ls = 0.f, ls2 = 0.f;
        int cg = -1;
        float ps = 0.f;
#pragma unroll
        for (int rt = 0; rt < 2; ++rt) {
#pragma unroll
            for (int reg = 0; reg < 4; ++reg) {
                int lrow = rt * 16 + quad * 4 + reg;
                float v = acc[rt][ct][reg] + bv;
                if constexpr (RELU_OUT) v = fmaxf(v, 0.f);
                if constexpr (STATS) {
                    if (row_base + lrow < N) { ls += v; ls2 += v * v; }
                }
                if constexpr (POOL) {
                    int d = dg[rt * 4 + reg];
                    if (d != cg) {
                        if (cg >= 0) atomicAdd(&s_pool[cg & (GSPAN - 1)][col], ps);
                        cg = d; ps = 0.f;
                    }
                    if (d >= 0) ps += v;
                } else {
                    tile[lrow * TSTR + l16] = f2bf(v);
                }
            }
        }
        if constexpr (POOL) {
            if (cg >= 0) atomicAdd(&s_pool[cg & (GSPAN - 1)][col], ps);
        }
        if constexpr (STATS) {
            ls += __shfl_xor(ls, 16);
            ls += __shfl_xor(ls, 32);
            ls2 += __shfl_xor(ls2, 16);
            ls2 += __shfl_xor(ls2, 32);
            if (quad == 0) {
                atomicAdd(&s_aux[col], ls);
                atomicAdd(&s_aux[NFEAT + col], ls2);
            }
        }
        if constexpr (!POOL) {
            // wave-private tile: same-wave DS ordering suffices, no barrier
            uint4 val = *(const uint4*)(tile + row2 * TSTR + half * 8);
            int grow = row_base + row2;
            if (grow < N) {
                int col0 = ct * 16 + half * 8;
                if constexpr (FRAG_OUT) {
                    size_t addr = ((size_t)(grow >> 4) * 4 + (col0 >> 5)) * 512 +
                                  (size_t)((((col0 >> 3) & 3) * 16 + (grow & 15)) * 8);
                    *(uint4*)(C + addr) = val;
                } else {
                    *(uint4*)(C + (size_t)grow * NFEAT + col0) = val;
                }
            }
        }
    }

    if constexpr (STATS) {
        __syncthreads();
        if (tid < NFEAT) {
            atomicAdd(&stats[tid], s_aux[tid]);
            atomicAdd(&stats[NFEAT + tid], s_aux[NFEAT + tid]);
        }
    }
    if constexpr (POOL) {
        __syncthreads();
        for (int i = tid; i < GSPAN * NFEAT; i += 256) {
            float v = s_pool[i >> 7][i & 127];
            if (v != 0.f) {
                int gg = gbase + (i >> 7);
                if (gg < NGRAPHS) atomicAdd(&pooled[gg * NFEAT + (i & 127)], v);
            }
        }
    }
}

__global__ void k_final(const float* __restrict__ pooled, const float* __restrict__ Wl,
                        const float* __restrict__ bl, float* __restrict__ out) {
    int idx = blockIdx.x * blockDim.x + threadIdx.x;
    if (idx >= NGRAPHS * TGRAPH) return;
    int g = idx / TGRAPH, t = idx % TGRAPH;
    const float* p = pooled + (size_t)g * NFEAT;
    float acc = bl[t];
#pragma unroll 16
    for (int k = 0; k < NFEAT; ++k) acc += p[k] * Wl[k * TGRAPH + t];
    out[idx] = acc;
}

extern "C" void kernel_launch(void* const* d_in, const int* in_sizes, int n_in,
                              void* d_out, int out_size, void* d_ws, size_t ws_size,
                              hipStream_t stream) {
    const float* x = (const float*)d_in[0];
    const int* ei = (const int*)d_in[1];
    const int* batch = (const int*)d_in[2];
    const float* W1a = (const float*)d_in[3];
    const float* b1a = (const float*)d_in[4];
    const float* g1 = (const float*)d_in[5];
    const float* bt1 = (const float*)d_in[6];
    const float* W1b = (const float*)d_in[7];
    const float* b1b = (const float*)d_in[8];
    const float* W2a = (const float*)d_in[9];
    const float* b2a = (const float*)d_in[10];
    const float* g2 = (const float*)d_in[11];
    const float* bt2 = (const float*)d_in[12];
    const float* W2b = (const float*)d_in[13];
    const float* b2b = (const float*)d_in[14];
    const float* Wl = (const float*)d_in[15];
    const float* bl = (const float*)d_in[16];
    float* out = (float*)d_out;

    int N = in_sizes[2];
    int E = in_sizes[1] / 2;
    int nb = (N + 511) >> 9;
    const int* src = ei;
    const int* dst = ei + E;

    int gemmBlocks = (N + 127) / 128;
    int padRows = gemmBlocks * 128;
    int aggBlocks = (N + 63) / 64;

    char* ws = (char*)d_ws;
    size_t off = 0;
    auto alloc = [&](size_t bytes) -> void* {
        void* p = ws + off;
        off = (off + bytes + 255) & ~(size_t)255;
        return p;
    };
    short* xbf = (short*)alloc((size_t)N * NFEAT * 2);        // row-major (gather input)
    short* ybf = (short*)alloc((size_t)padRows * NFEAT * 2);  // frag layout
    short* hbf = (short*)alloc((size_t)N * NFEAT * 2);        // row-major (gather input)
    short* Wf = (short*)alloc((size_t)4 * 16384 * 2);
    int* adj = (int*)alloc((size_t)E * 4);
    int2* binned = (int2*)alloc((size_t)E * 8);
    int* rowptr = (int*)alloc((size_t)(N + 1) * 4);
    int* bbase = (int*)alloc(257 * 4);
    int* cur256 = (int*)alloc(256 * 4);
    // zero-region: bhist + stats1 + stats2 + pooled
    int* bhist = (int*)alloc(256 * 4);
    float* stats1 = (float*)alloc(256 * 4);
    float* stats2 = (float*)alloc(256 * 4);
    float* pooled = (float*)alloc((size_t)NGRAPHS * NFEAT * 4);
    size_t zbytes = (char*)(pooled + (size_t)NGRAPHS * NFEAT) - (char*)bhist;

    hipMemsetAsync(bhist, 0, zbytes, stream);

    // ---- merged hist + dtype prep (one dispatch), then CSR chain ----
    int n4 = N * NFEAT / 4;
    int prepTot = n4 + 4 * 16384;
    int hb = 784;
    k_prep_hist<<<hb + (prepTot + 255) / 256, 256, 0, stream>>>(
        dst, bhist, E, hb, x, xbf, W1a, W1b, W2a, W2b, Wf, n4);
    k_bucket_scan<<<1, 256, 0, stream>>>(bhist, bbase, cur256, E);
    k_bin_scatter<<<(E + BIN_CHUNK - 1) / BIN_CHUNK, 256, 0, stream>>>(src, dst, cur256, binned, E);
    k_bucket_csr<<<nb, 512, 0, stream>>>(binned, bbase, rowptr, adj, N, E, nb);

    // ---- layer 1: fused aggregate+GEMM-a, then BN+ReLU GEMM-b ----
    k_agg_gemm<<<aggBlocks, 256, 0, stream>>>(xbf, rowptr, adj, Wf + 0 * 16384, b1a,
                                              stats1, ybf, N);
    k_gemm_mfma<true, true, false, false, false><<<gemmBlocks, 256, 0, stream>>>(
        ybf, Wf + 1 * 16384, b1b, stats1, g1, bt1, nullptr, nullptr, hbf, N);

    // ---- layer 2 (GEMM-b pools directly) ----
    k_agg_gemm<<<aggBlocks, 256, 0, stream>>>(hbf, rowptr, adj, Wf + 2 * 16384, b2a,
                                              stats2, ybf, N);
    k_gemm_mfma<true, true, false, false, true><<<gemmBlocks, 256, 0, stream>>>(
        ybf, Wf + 3 * 16384, b2b, stats2, g2, bt2, batch, pooled, nullptr, N);

    // ---- classifier ----
    k_final<<<(NGRAPHS * TGRAPH + 255) / 256, 256, 0, stream>>>(pooled, Wl, bl, out);
}